// Round 12
// baseline (717.724 us; speedup 1.0000x reference)
//
#include <hip/hip_runtime.h>

// ---------------------------------------------------------------------------
// QGaloreLinear: y = x @ dequant(qw)^T + bias.  M=8192, N=4096, K=4096.
// R12: R11's GEMM skeleton (R7 schedule, proven) + x-convert FUSED into
//   A-staging (T14 reg-stage: glA issue early, cvt+swizzled ds_write 2 phases
//   later). Prep shrinks to W-only (288->96MB, 46->~16us).
//   Ledger (vmcnt = wait-until-<=N, per-wave issue {q3:glA0x4, q0:glA1x4,
//   q1:gldsB0x2, q2:gldsB1x2}): q1 vmcnt(6) retires A0(kt+1) loads before
//   write; q2 vmcnt(4) retires A1(kt+1); lgkmcnt(0) @q2-end drains A writes
//   before q3's BAR (cross-wave rule: reads of coop-written LDS only after a
//   barrier following ALL waves' waits). Overwrite-after-read >= 4 barriers.
//   NOTE: __launch_bounds__(512,2) is load-bearing (R6: (512,4) spilled).
// ---------------------------------------------------------------------------

typedef __attribute__((ext_vector_type(8))) short bf16x8;
typedef __attribute__((ext_vector_type(8))) unsigned short ushort8;
typedef __attribute__((ext_vector_type(4))) float f32x4;

__device__ inline unsigned short f2bf(float f) {
  union { float f; unsigned int u; } v; v.f = f;
  unsigned int u = v.u;
  return (unsigned short)((u + 0x7fffu + ((u >> 16) & 1u)) >> 16);
}

// ---- kernel 1: dequantize int32 qweight -> bf16 Wb[N][K] (W only) -----------
__global__ void dequant_w_kernel(const int* __restrict__ q,
                                 const float* __restrict__ sc,
                                 const float* __restrict__ zp,
                                 ushort8* __restrict__ wb, int total8) {
  int t = blockIdx.x * blockDim.x + threadIdx.x;
  if (t >= total8) return;
  const int4* q4 = (const int4*)q + (size_t)t * 2;
  int4 a = q4[0];
  int4 b = q4[1];
  int g = t >> 5;
  float s = sc[g], z = zp[g];
  ushort8 o;
  o[0] = f2bf(((float)a.x - z) * s);
  o[1] = f2bf(((float)a.y - z) * s);
  o[2] = f2bf(((float)a.z - z) * s);
  o[3] = f2bf(((float)a.w - z) * s);
  o[4] = f2bf(((float)b.x - z) * s);
  o[5] = f2bf(((float)b.y - z) * s);
  o[6] = f2bf(((float)b.z - z) * s);
  o[7] = f2bf(((float)b.w - z) * s);
  wb[t] = o;
}

// ---- kernel 2: 256x256 GEMM, A = fp32 x converted in-staging ----------------
#define BM 256
#define BN 256
#define BK 64

#define BAR() asm volatile("s_barrier" ::: "memory")
#define MFMA16(d, x, y) d = __builtin_amdgcn_mfma_f32_16x16x32_bf16(x, y, d, 0, 0, 0)

__device__ inline void gload_lds16(const void* g, void* l) {
  __builtin_amdgcn_global_load_lds(
      (const __attribute__((address_space(1))) unsigned int*)g,
      (__attribute__((address_space(3))) unsigned int*)l, 16, 0, 0);
}

// B staging (unchanged): 128x64 bf16 half-tile, pre-swizzled global slots.
__device__ inline void stage_half(const unsigned short* __restrict__ gsrc,
                                  char* lds_region, int K, int wave, int lane) {
  const int l3  = lane >> 3;
  const int swz = ((lane & 7) ^ l3) * 8;
#pragma unroll
  for (int inst = 0; inst < 2; ++inst) {
    const int row = inst * 64 + wave * 8 + l3;
    gload_lds16(gsrc + (size_t)row * K + swz,
                lds_region + (size_t)(inst * 512 + wave * 64) * 16);
  }
}

__global__ __launch_bounds__(512, 2)
void gemm256_kernel(const float* __restrict__ X,           // x, M x K fp32
                    const unsigned short* __restrict__ Bw, // Wb, N x K bf16
                    const float* __restrict__ bias,
                    float* __restrict__ C,
                    int M, int N, int K) {
  extern __shared__ char lds[];   // buf: A0@0 A1@16K B0@32K B1@48K; dbuf @64K
  const int t    = threadIdx.x;
  const int lane = t & 63;
  const int wave = t >> 6;
  const int wm   = wave >> 2;
  const int wn   = wave & 3;
  const int lr   = lane & 15;
  const int hi   = lane >> 4;
  const int l7   = lane & 7;

  // A reg-staging geometry: thread t -> region row arow, 2 logical 16B slots
  const int arow  = t >> 2;            // 0..127
  const int asl0  = (t & 3) * 2;       // logical slots {0,2,4,6}
  const int asl1  = asl0 + 1;
  const int arow7 = arow & 7;
  const int aoff0 = (asl0 ^ arow7) * 16;   // swizzled write byte-offsets
  const int aoff1 = (asl1 ^ arow7) * 16;

  // T1: bijective XCD swizzle (nwg % 8 == 0)
  const int nwg = gridDim.x;
  const int cpx = nwg >> 3;
  const int bid = blockIdx.x;
  const int swzb = (bid & 7) * cpx + (bid >> 3);
  const int ntn = N / BN;
  const int bm = swzb / ntn, bn = swzb % ntn;
  const int row0 = bm * BM, col0 = bn * BN;

  const int NT = K / BK;   // 64

  const int soff0 = ((hi) ^ l7) * 16;
  const int soff1 = ((4 + hi) ^ l7) * 16;

  const float* Ax = X + (size_t)row0 * K;
  const unsigned short* Bsrc = Bw + (size_t)col0 * K;

#define STAGE_B0(buf, kt) stage_half(Bsrc + (size_t)(kt) * BK,           (buf) + 32768, K, wave, lane)
#define STAGE_B1(buf, kt) stage_half(Bsrc + (size_t)128 * K + (kt) * BK, (buf) + 49152, K, wave, lane)

  // A: issue 4 fp32x4 loads for half-tile `half` of K-tile kt
#define A_ISSUE(va, vb, vc, vd, half, kt) {                                   \
    const float* g_ = Ax + ((size_t)((half) * 128 + arow)) * K + (size_t)(kt) * BK; \
    va = *(const float4*)(g_ + asl0 * 8);                                     \
    vb = *(const float4*)(g_ + asl0 * 8 + 4);                                 \
    vc = *(const float4*)(g_ + asl1 * 8);                                     \
    vd = *(const float4*)(g_ + asl1 * 8 + 4);                                 \
  }
  // A: convert 16 fp32 -> 16 bf16, write 2 swizzled b128 slots
#define A_WRITE(va, vb, vc, vd, regionp) {                                    \
    ushort8 o0, o1;                                                           \
    o0[0] = f2bf(va.x); o0[1] = f2bf(va.y); o0[2] = f2bf(va.z); o0[3] = f2bf(va.w); \
    o0[4] = f2bf(vb.x); o0[5] = f2bf(vb.y); o0[6] = f2bf(vb.z); o0[7] = f2bf(vb.w); \
    o1[0] = f2bf(vc.x); o1[1] = f2bf(vc.y); o1[2] = f2bf(vc.z); o1[3] = f2bf(vc.w); \
    o1[4] = f2bf(vd.x); o1[5] = f2bf(vd.y); o1[6] = f2bf(vd.z); o1[7] = f2bf(vd.w); \
    *(ushort8*)((regionp) + arow * 128 + aoff0) = o0;                         \
    *(ushort8*)((regionp) + arow * 128 + aoff1) = o1;                         \
  }

  f32x4 acc[8][4] = {};
  bf16x8 a[4][2];
  bf16x8 b[4][2];
  float4 al0, al1, al2, al3;   // A0 pipeline: issued @q3, written @q1(next kt)
  float4 bl0, bl1, bl2, bl3;   // A1 pipeline: issued @q0, written @q2

#define READ_A(mh, bufp) {                                                    \
    const char* Ab_ = (const char*)(bufp) + wm * 16384 + (mh) * 8192;         \
    _Pragma("unroll")                                                         \
    for (int mm = 0; mm < 4; ++mm) {                                          \
      const int r_ = (mm * 16 + lr) * 128;                                    \
      a[mm][0] = *(const bf16x8*)(Ab_ + r_ + soff0);                          \
      a[mm][1] = *(const bf16x8*)(Ab_ + r_ + soff1);                          \
    } }
#define READ_B(nh, bufp) {                                                    \
    const char* Bb_ = (const char*)(bufp) + 32768 + wn * 8192;                \
    _Pragma("unroll")                                                         \
    for (int nn = 0; nn < 2; ++nn) {                                          \
      const int r_ = (((nh) * 2 + nn) * 16 + lr) * 128;                       \
      b[(nh) * 2 + nn][0] = *(const bf16x8*)(Bb_ + r_ + soff0);               \
      b[(nh) * 2 + nn][1] = *(const bf16x8*)(Bb_ + r_ + soff1);               \
    } }
#define MFMA_QUAD(mh, nh)                                                     \
    __builtin_amdgcn_s_setprio(1);                                            \
    _Pragma("unroll")                                                         \
    for (int mm = 0; mm < 4; ++mm)                                            \
      _Pragma("unroll")                                                       \
      for (int nn = 0; nn < 2; ++nn) {                                        \
        MFMA16(acc[(mh) * 4 + mm][(nh) * 2 + nn], a[mm][0], b[(nh) * 2 + nn][0]); \
        MFMA16(acc[(mh) * 4 + mm][(nh) * 2 + nn], a[mm][1], b[(nh) * 2 + nn][1]); \
      }                                                                       \
    __builtin_amdgcn_s_setprio(0);

#define KT_BODY(buf, nbuf, kt, GUARDED)                                       \
  {                                                                           \
    /* q0: MFMA(m0,n01) ; issue glA1(kt+1) ; read b23 */                      \
    BAR();                                                                    \
    MFMA_QUAD(0, 0);                                                          \
    if (!(GUARDED) || (kt) + 1 < NT) A_ISSUE(bl0, bl1, bl2, bl3, 1, (kt) + 1);\
    READ_B(1, buf);                                                           \
    /* q1: MFMA(m0,n23) ; stage B0(kt+2) ; vmcnt ; write A0(kt+1)->nbuf ;     \
       read a(m1) */                                                          \
    BAR();                                                                    \
    MFMA_QUAD(0, 1);                                                          \
    if (!(GUARDED) || (kt) + 2 < NT) STAGE_B0(buf, (kt) + 2);                 \
    if (!(GUARDED)) { asm volatile("s_waitcnt vmcnt(6)" ::: "memory"); }      \
    else if ((kt) + 1 < NT) { asm volatile("s_waitcnt vmcnt(0)" ::: "memory"); } \
    if (!(GUARDED) || (kt) + 1 < NT) A_WRITE(al0, al1, al2, al3, (nbuf));     \
    READ_A(1, buf);                                                           \
    /* q2: MFMA(m1,n01) ; stage B1(kt+2) ; vmcnt ; write A1(kt+1)->nbuf ;     \
       lgkm0 */                                                               \
    BAR();                                                                    \
    MFMA_QUAD(1, 0);                                                          \
    if (!(GUARDED) || (kt) + 2 < NT) STAGE_B1(buf, (kt) + 2);                 \
    if (!(GUARDED)) { asm volatile("s_waitcnt vmcnt(4)" ::: "memory"); }      \
    else { asm volatile("s_waitcnt vmcnt(0)" ::: "memory"); }                 \
    if (!(GUARDED) || (kt) + 1 < NT) A_WRITE(bl0, bl1, bl2, bl3, (nbuf) + 16384); \
    asm volatile("s_waitcnt lgkmcnt(0)" ::: "memory");                        \
    /* q3: MFMA(m1,n23) ; issue glA0(kt+2) ; read next-kt a(m0),b(n0) */      \
    BAR();                                                                    \
    MFMA_QUAD(1, 1);                                                          \
    if (!(GUARDED) || (kt) + 2 < NT) A_ISSUE(al0, al1, al2, al3, 0, (kt) + 2);\
    if (!(GUARDED) || (kt) + 1 < NT) {                                        \
      READ_A(0, nbuf);                                                        \
      READ_B(0, nbuf);                                                        \
    }                                                                         \
  }

  // ---- prologue ----
  char* buf0 = lds;
  char* buf1 = lds + 65536;
  {
    float4 p0, p1, p2, p3, r0, r1, r2, r3;
    A_ISSUE(p0, p1, p2, p3, 0, 0);
    A_ISSUE(r0, r1, r2, r3, 1, 0);
    asm volatile("s_waitcnt vmcnt(0)" ::: "memory");
    A_WRITE(p0, p1, p2, p3, buf0);
    A_WRITE(r0, r1, r2, r3, buf0 + 16384);
  }
  STAGE_B0(buf0, 0); STAGE_B1(buf0, 0);
  STAGE_B0(buf1, 1); STAGE_B1(buf1, 1);
  A_ISSUE(al0, al1, al2, al3, 0, 1);
  // outstanding: glds 8 + glA0(1) 4 = 12 -> <=8 retires B0(0),B1(0)
  asm volatile("s_waitcnt vmcnt(8) lgkmcnt(0)" ::: "memory");
  BAR();
  READ_A(0, buf0);
  READ_B(0, buf0);

  // ---- main: branchless pairs (kt = 0 .. NT-4) ----
  int kt = 0;
  for (; kt + 3 < NT; kt += 2) {
    KT_BODY(buf0, buf1, kt, 0);
    KT_BODY(buf1, buf0, kt + 1, 0);
  }
  // ---- tail: last 2 K-tiles, guarded ----
  for (; kt < NT; ++kt) {
    char* buf  = lds + ((kt & 1) << 16);
    char* nbuf = lds + (((kt & 1) ^ 1) << 16);
    KT_BODY(buf, nbuf, kt, 1);
  }

  // ---- epilogue: per-wave LDS transpose -> coalesced float4 C stores ----
  BAR();
  {
    char* myl = lds + wave * 16384;      // 272B row stride
    const int gcol = col0 + wn * 64 + lr * 4;
    const float4 bv4 = *(const float4*)&bias[gcol];
#pragma unroll
    for (int mp = 0; mp < 4; ++mp) {
#pragma unroll
      for (int mm = 0; mm < 2; ++mm)
#pragma unroll
        for (int n = 0; n < 4; ++n)
#pragma unroll
          for (int j = 0; j < 4; ++j)
            *(float*)(myl + (mm * 16 + hi * 4 + j) * 272 + (n * 16 + lr) * 4)
                = acc[mp * 2 + mm][n][j];
#pragma unroll
      for (int r = 0; r < 8; ++r) {
        const int row = r * 4 + hi;
        float4 v = *(const float4*)(myl + row * 272 + lr * 16);
        v.x += bv4.x; v.y += bv4.y; v.z += bv4.z; v.w += bv4.w;
        const int grow = row0 + wm * 128 + mp * 32 + row;
        *(float4*)&C[(size_t)grow * N + gcol] = v;
      }
    }
  }
#undef STAGE_B0
#undef STAGE_B1
#undef A_ISSUE
#undef A_WRITE
#undef READ_A
#undef READ_B
#undef MFMA_QUAD
#undef KT_BODY
}

// ---------------------------------------------------------------------------
extern "C" void kernel_launch(void* const* d_in, const int* in_sizes, int n_in,
                              void* d_out, int out_size, void* d_ws, size_t ws_size,
                              hipStream_t stream) {
  const float* x      = (const float*)d_in[0];
  const int*   qw     = (const int*)d_in[1];
  const float* scales = (const float*)d_in[2];
  const float* zeros  = (const float*)d_in[3];
  const float* bias   = (const float*)d_in[4];
  float* out = (float*)d_out;

  const int OUT = in_sizes[4];                 // 4096
  const int IN  = in_sizes[1] / OUT;           // 4096
  const int M   = in_sizes[0] / IN;            // 8192

  unsigned short* wb = (unsigned short*)d_ws;  // OUT*IN bf16

  {
    int total8 = OUT * IN / 8;
    dequant_w_kernel<<<(total8 + 255) / 256, 256, 0, stream>>>(
        qw, scales, zeros, (ushort8*)wb, total8);
  }
  {
    hipFuncSetAttribute((const void*)gemm256_kernel,
                        hipFuncAttributeMaxDynamicSharedMemorySize, 131072);
    dim3 grid((M / BM) * (OUT / BN));
    gemm256_kernel<<<grid, 512, 131072, stream>>>(x, wb, bias, out, M, OUT, IN);
  }
}

// Round 13
// 264.003 us; speedup vs baseline: 2.7186x; 2.7186x over previous
//
#include <hip/hip_runtime.h>

// ---------------------------------------------------------------------------
// QGaloreLinear: y = x @ dequant(qw)^T + bias.  M=8192, N=4096, K=4096.
// R13: REVERT to R11 (best measured: 263.6us; GEMM 219us, prep at BW floor).
//   R12 lesson (recorded): reg-staged A (T14) adds +32 live VGPRs across the
//   MFMA clusters -> accumulator spill (WRITE_SIZE 136->735MB, MfmaUtil 15%).
//   With a 128-VGPR accumulator, staging MUST be global_load_lds.
//   Schedule rules proven this session:
//     - R7 KT_BODY is the fixed point: nbuf reads only at q3 (one barrier
//       after ALL waves' vmcnt — vmcnt is per-wave, cross-wave RAW rule).
//     - 2-barrier overwrite-after-read separation is load-bearing (R8 raced).
//     - __launch_bounds__(512,2) is load-bearing (R6: (512,4) spilled).
//   Epilogue: per-wave 16KB LDS transpose (272B rows) -> float4 full-line C
//   stores (WRITE_SIZE 162->136MB). Prep: fused dequant+convert, grid-stride.
// ---------------------------------------------------------------------------

typedef __attribute__((ext_vector_type(8))) short bf16x8;
typedef __attribute__((ext_vector_type(8))) unsigned short ushort8;
typedef __attribute__((ext_vector_type(4))) float f32x4;

__device__ inline unsigned short f2bf(float f) {
  union { float f; unsigned int u; } v; v.f = f;
  unsigned int u = v.u;
  return (unsigned short)((u + 0x7fffu + ((u >> 16) & 1u)) >> 16);
}

// ---- kernel 1: fused  dequant(W)->bf16  +  convert(x)->bf16 -----------------
__global__ void prep_kernel(const int* __restrict__ q,
                            const float* __restrict__ sc,
                            const float* __restrict__ zp,
                            ushort8* __restrict__ wb,
                            const float* __restrict__ x,
                            ushort8* __restrict__ xb,
                            int nw8, int nx8) {
  const int stride = gridDim.x * blockDim.x;
  for (int t = blockIdx.x * blockDim.x + threadIdx.x; t < nw8 + nx8; t += stride) {
    if (t < nw8) {
      const int4* q4 = (const int4*)q + (size_t)t * 2;
      int4 a = q4[0];
      int4 b = q4[1];
      int g = t >> 5;
      float s = sc[g], z = zp[g];
      ushort8 o;
      o[0] = f2bf(((float)a.x - z) * s);
      o[1] = f2bf(((float)a.y - z) * s);
      o[2] = f2bf(((float)a.z - z) * s);
      o[3] = f2bf(((float)a.w - z) * s);
      o[4] = f2bf(((float)b.x - z) * s);
      o[5] = f2bf(((float)b.y - z) * s);
      o[6] = f2bf(((float)b.z - z) * s);
      o[7] = f2bf(((float)b.w - z) * s);
      wb[t] = o;
    } else {
      int u = t - nw8;
      const float4* x4 = (const float4*)x + (size_t)u * 2;
      float4 a = x4[0];
      float4 b = x4[1];
      ushort8 o;
      o[0] = f2bf(a.x); o[1] = f2bf(a.y); o[2] = f2bf(a.z); o[3] = f2bf(a.w);
      o[4] = f2bf(b.x); o[5] = f2bf(b.y); o[6] = f2bf(b.z); o[7] = f2bf(b.w);
      xb[u] = o;
    }
  }
}

// ---- kernel 2: 256x256 single-barrier-phase bf16 GEMM -----------------------
#define BM 256
#define BN 256
#define BK 64

#define BAR() asm volatile("s_barrier" ::: "memory")
#define MFMA16(d, x, y) d = __builtin_amdgcn_mfma_f32_16x16x32_bf16(x, y, d, 0, 0, 0)

__device__ inline void gload_lds16(const void* g, void* l) {
  __builtin_amdgcn_global_load_lds(
      (const __attribute__((address_space(1))) unsigned int*)g,
      (__attribute__((address_space(3))) unsigned int*)l, 16, 0, 0);
}

// Stage one 128-row x 64-col bf16 half-tile (16 KiB). Global 16B-slot is
// pre-swizzled (slot ^ (row&7)); LDS dest linear (rule #21 both-sides).
__device__ inline void stage_half(const unsigned short* __restrict__ gsrc,
                                  char* lds_region, int K, int wave, int lane) {
  const int l3  = lane >> 3;
  const int swz = ((lane & 7) ^ l3) * 8;
#pragma unroll
  for (int inst = 0; inst < 2; ++inst) {
    const int row = inst * 64 + wave * 8 + l3;
    gload_lds16(gsrc + (size_t)row * K + swz,
                lds_region + (size_t)(inst * 512 + wave * 64) * 16);
  }
}

__global__ __launch_bounds__(512, 2)
void gemm256_kernel(const unsigned short* __restrict__ A,  // Xb, M x K
                    const unsigned short* __restrict__ B,  // Wb, N x K
                    const float* __restrict__ bias,
                    float* __restrict__ C,
                    int M, int N, int K) {
  extern __shared__ char lds[];   // buf: A0@0 A1@16K B0@32K B1@48K; dbuf @64K
  const int t    = threadIdx.x;
  const int lane = t & 63;
  const int wave = t >> 6;
  const int wm   = wave >> 2;
  const int wn   = wave & 3;
  const int lr   = lane & 15;
  const int hi   = lane >> 4;
  const int l7   = lane & 7;

  // T1: bijective XCD swizzle (nwg % 8 == 0)
  const int nwg = gridDim.x;
  const int cpx = nwg >> 3;
  const int bid = blockIdx.x;
  const int swzb = (bid & 7) * cpx + (bid >> 3);
  const int ntn = N / BN;
  const int bm = swzb / ntn, bn = swzb % ntn;
  const int row0 = bm * BM, col0 = bn * BN;

  const int NT = K / BK;   // 64

  const int soff0 = ((hi) ^ l7) * 16;
  const int soff1 = ((4 + hi) ^ l7) * 16;

  const unsigned short* Asrc = A + (size_t)row0 * K;
  const unsigned short* Bsrc = B + (size_t)col0 * K;

#define STAGE_A0(buf, kt) stage_half(Asrc + (size_t)(kt) * BK,           (buf),         K, wave, lane)
#define STAGE_A1(buf, kt) stage_half(Asrc + (size_t)128 * K + (kt) * BK, (buf) + 16384, K, wave, lane)
#define STAGE_B0(buf, kt) stage_half(Bsrc + (size_t)(kt) * BK,           (buf) + 32768, K, wave, lane)
#define STAGE_B1(buf, kt) stage_half(Bsrc + (size_t)128 * K + (kt) * BK, (buf) + 49152, K, wave, lane)

  f32x4 acc[8][4] = {};
  bf16x8 a[4][2];   // current m-half, 4 frags x 2 ks
  bf16x8 b[4][2];   // all 4 n-frags of this kt

#define READ_A(mh, bufp) {                                                    \
    const char* Ab_ = (const char*)(bufp) + wm * 16384 + (mh) * 8192;         \
    _Pragma("unroll")                                                         \
    for (int mm = 0; mm < 4; ++mm) {                                          \
      const int r_ = (mm * 16 + lr) * 128;                                    \
      a[mm][0] = *(const bf16x8*)(Ab_ + r_ + soff0);                          \
      a[mm][1] = *(const bf16x8*)(Ab_ + r_ + soff1);                          \
    } }
#define READ_B(nh, bufp) {                                                    \
    const char* Bb_ = (const char*)(bufp) + 32768 + wn * 8192;                \
    _Pragma("unroll")                                                         \
    for (int nn = 0; nn < 2; ++nn) {                                          \
      const int r_ = (((nh) * 2 + nn) * 16 + lr) * 128;                       \
      b[(nh) * 2 + nn][0] = *(const bf16x8*)(Bb_ + r_ + soff0);               \
      b[(nh) * 2 + nn][1] = *(const bf16x8*)(Bb_ + r_ + soff1);               \
    } }
#define MFMA_QUAD(mh, nh)                                                     \
    __builtin_amdgcn_s_setprio(1);                                            \
    _Pragma("unroll")                                                         \
    for (int mm = 0; mm < 4; ++mm)                                            \
      _Pragma("unroll")                                                       \
      for (int nn = 0; nn < 2; ++nn) {                                        \
        MFMA16(acc[(mh) * 4 + mm][(nh) * 2 + nn], a[mm][0], b[(nh) * 2 + nn][0]); \
        MFMA16(acc[(mh) * 4 + mm][(nh) * 2 + nn], a[mm][1], b[(nh) * 2 + nn][1]); \
      }                                                                       \
    __builtin_amdgcn_s_setprio(0);

  // One K-tile body (R7-exact). nbuf reads ONLY at q3 (one barrier after all
  // waves' vmcnt(4) at q2 — the per-wave-vmcnt cross-wave RAW rule).
#define KT_BODY(buf, nbuf, kt, GUARDED)                                       \
  {                                                                           \
    /* q0: MFMA(m0,n01) ; stage A1(kt+1)->nbuf ; read b23 */                  \
    BAR();                                                                    \
    MFMA_QUAD(0, 0);                                                          \
    if (!(GUARDED) || (kt) + 1 < NT) STAGE_A1(nbuf, (kt) + 1);                \
    READ_B(1, buf);                                                           \
    /* q1: MFMA(m0,n23) ; stage B0(kt+2)->buf ; read a(m1) */                 \
    BAR();                                                                    \
    MFMA_QUAD(0, 1);                                                          \
    if (!(GUARDED) || (kt) + 2 < NT) STAGE_B0(buf, (kt) + 2);                 \
    READ_A(1, buf);                                                           \
    /* q2: MFMA(m1,n01) ; stage B1(kt+2)->buf ; vmcnt */                      \
    BAR();                                                                    \
    MFMA_QUAD(1, 0);                                                          \
    if (!(GUARDED) || (kt) + 2 < NT) {                                        \
      STAGE_B1(buf, (kt) + 2);                                                \
      asm volatile("s_waitcnt vmcnt(4)" ::: "memory");                        \
    } else {                                                                  \
      asm volatile("s_waitcnt vmcnt(0)" ::: "memory");                        \
    }                                                                         \
    /* q3: MFMA(m1,n23) ; stage A0(kt+2)->buf ; read next-kt a(m0),b(n0) */   \
    BAR();                                                                    \
    MFMA_QUAD(1, 1);                                                          \
    if (!(GUARDED) || (kt) + 2 < NT) STAGE_A0(buf, (kt) + 2);                 \
    if (!(GUARDED) || (kt) + 1 < NT) {                                        \
      READ_A(0, nbuf);                                                        \
      READ_B(0, nbuf);                                                        \
    }                                                                         \
  }

  // ---- prologue: stage buf0 fully + buf1 {A0,B0,B1}; A1(1) comes @q0(0) ----
  char* buf0 = lds;
  char* buf1 = lds + 65536;
  STAGE_A0(buf0, 0); STAGE_A1(buf0, 0); STAGE_B0(buf0, 0); STAGE_B1(buf0, 0);
  STAGE_A0(buf1, 1); STAGE_B0(buf1, 1); STAGE_B1(buf1, 1);
  asm volatile("s_waitcnt vmcnt(6)" ::: "memory");
  BAR();
  READ_A(0, buf0);
  READ_B(0, buf0);

  // ---- main: branchless pairs (kt = 0 .. NT-4) ----
  int kt = 0;
  for (; kt + 3 < NT; kt += 2) {
    KT_BODY(buf0, buf1, kt, 0);
    KT_BODY(buf1, buf0, kt + 1, 0);
  }
  // ---- tail: last 2 K-tiles, guarded ----
  for (; kt < NT; ++kt) {
    char* buf  = lds + ((kt & 1) << 16);
    char* nbuf = lds + (((kt & 1) ^ 1) << 16);
    KT_BODY(buf, nbuf, kt, 1);
  }

  // ---- epilogue: per-wave LDS transpose -> coalesced float4 C stores ----
  BAR();
  {
    char* myl = lds + wave * 16384;      // 272B row stride: 64 f32 + 16B pad
    const int gcol = col0 + wn * 64 + lr * 4;
    const float4 bv4 = *(const float4*)&bias[gcol];
#pragma unroll
    for (int mp = 0; mp < 4; ++mp) {     // 32-row chunk = acc frags 2mp,2mp+1
#pragma unroll
      for (int mm = 0; mm < 2; ++mm)
#pragma unroll
        for (int n = 0; n < 4; ++n)
#pragma unroll
          for (int j = 0; j < 4; ++j)
            *(float*)(myl + (mm * 16 + hi * 4 + j) * 272 + (n * 16 + lr) * 4)
                = acc[mp * 2 + mm][n][j];
#pragma unroll
      for (int r = 0; r < 8; ++r) {
        const int row = r * 4 + hi;      // 0..31
        float4 v = *(const float4*)(myl + row * 272 + lr * 16);
        v.x += bv4.x; v.y += bv4.y; v.z += bv4.z; v.w += bv4.w;
        const int grow = row0 + wm * 128 + mp * 32 + row;
        *(float4*)&C[(size_t)grow * N + gcol] = v;
      }
    }
  }
#undef STAGE_A0
#undef STAGE_A1
#undef STAGE_B0
#undef STAGE_B1
#undef READ_A
#undef READ_B
#undef MFMA_QUAD
#undef KT_BODY
}

// ---------------------------------------------------------------------------
extern "C" void kernel_launch(void* const* d_in, const int* in_sizes, int n_in,
                              void* d_out, int out_size, void* d_ws, size_t ws_size,
                              hipStream_t stream) {
  const float* x      = (const float*)d_in[0];
  const int*   qw     = (const int*)d_in[1];
  const float* scales = (const float*)d_in[2];
  const float* zeros  = (const float*)d_in[3];
  const float* bias   = (const float*)d_in[4];
  float* out = (float*)d_out;

  const int OUT = in_sizes[4];                 // 4096
  const int IN  = in_sizes[1] / OUT;           // 4096
  const int M   = in_sizes[0] / IN;            // 8192

  unsigned short* wb = (unsigned short*)d_ws;                 // OUT*IN bf16
  unsigned short* xb = wb + (size_t)OUT * IN;                 // M*IN  bf16

  {
    int nw8 = OUT * IN / 8;                    // multiple of 256 -> no straddle
    int nx8 = (int)((size_t)M * IN / 8);
    prep_kernel<<<2048, 256, 0, stream>>>(
        qw, scales, zeros, (ushort8*)wb, x, (ushort8*)xb, nw8, nx8);
  }
  {
    hipFuncSetAttribute((const void*)gemm256_kernel,
                        hipFuncAttributeMaxDynamicSharedMemorySize, 131072);
    dim3 grid((M / BM) * (OUT / BN));
    gemm256_kernel<<<grid, 512, 131072, stream>>>(xb, wb, bias, out, M, OUT, IN);
  }
}